// Round 1
// baseline (4486.657 us; speedup 1.0000x reference)
//
#include <hip/hip_runtime.h>

#define N_NODES 50000
#define N_EDGES 800000
#define D_IN 16
#define HID 128
#define D_OUT 4
#define N_LAYERS 3
#define LN_EPS 1e-5f

// ---- degree (mean-agg normalizer) ----
__global__ void deg_kernel(const int* __restrict__ dst, float* __restrict__ deg) {
    int e = blockIdx.x * 256 + threadIdx.x;
    if (e < N_EDGES) atomicAdd(&deg[dst[e]], 1.0f);
}

__global__ void invdeg_kernel(float* __restrict__ deg) {
    int n = blockIdx.x * 256 + threadIdx.x;
    if (n < N_NODES) deg[n] = 1.0f / fmaxf(deg[n], 1.0f);
}

// ---- h = x @ W_in + b_in ----
__global__ void in_proj_kernel(const float* __restrict__ x, const float* __restrict__ W,
                               const float* __restrict__ b, float* __restrict__ h) {
    int node = blockIdx.x * 2 + (threadIdx.x >> 7);
    int j = threadIdx.x & 127;
    if (node >= N_NODES) return;
    float acc = b[j];
    #pragma unroll
    for (int k = 0; k < D_IN; ++k) acc += x[node * D_IN + k] * W[k * HID + j];
    h[node * HID + j] = acc;
}

// ---- hn = LN(h)*g + b : one wave per node, 4 nodes per block ----
__global__ void ln_kernel(const float* __restrict__ h, const float* __restrict__ g,
                          const float* __restrict__ b, float* __restrict__ hn) {
    int wave = threadIdx.x >> 6;
    int lane = threadIdx.x & 63;
    int node = blockIdx.x * 4 + wave;
    if (node >= N_NODES) return;
    const float* hr = h + (size_t)node * HID;
    float v0 = hr[lane], v1 = hr[lane + 64];
    float s = v0 + v1;
    #pragma unroll
    for (int o = 32; o > 0; o >>= 1) s += __shfl_xor(s, o, 64);
    float mu = s * (1.0f / HID);
    float d0 = v0 - mu, d1 = v1 - mu;
    float q = d0 * d0 + d1 * d1;
    #pragma unroll
    for (int o = 32; o > 0; o >>= 1) q += __shfl_xor(q, o, 64);
    float rstd = rsqrtf(q * (1.0f / HID) + LN_EPS);
    hn[(size_t)node * HID + lane]      = d0 * rstd * g[lane]      + b[lane];
    hn[(size_t)node * HID + lane + 64] = d1 * rstd * g[lane + 64] + b[lane + 64];
}

// ---- agg[dst] += hn[src] : 32 threads/edge, float4 loads, scalar atomics ----
__global__ void scatter_kernel(const int* __restrict__ src, const int* __restrict__ dst,
                               const float* __restrict__ hn, float* __restrict__ agg) {
    int t = blockIdx.x * 256 + threadIdx.x;   // up to 25.6M < 2^31
    int e = t >> 5;
    int l = (t & 31) * 4;
    if (e >= N_EDGES) return;
    int s = src[e], d = dst[e];
    const float4 v = *(const float4*)(hn + (size_t)s * HID + l);
    float* ag = agg + (size_t)d * HID + l;
    atomicAdd(ag + 0, v.x);
    atomicAdd(ag + 1, v.y);
    atomicAdd(ag + 2, v.z);
    atomicAdd(ag + 3, v.w);
}

// ---- h = relu(h + (agg*inv)@Wl + bl + hn@Wr) : 32-node tile, fp32 ----
__global__ __launch_bounds__(256) void conv_kernel(
    const float* __restrict__ hres, const float* __restrict__ hn,
    const float* __restrict__ agg, const float* __restrict__ invdeg,
    const float* __restrict__ Wl, const float* __restrict__ bl,
    const float* __restrict__ Wr, float* __restrict__ hout) {
    __shared__ float s_a[32 * HID];
    __shared__ float s_h[32 * HID];
    int tid = threadIdx.x;
    int n0 = blockIdx.x * 32;

    #pragma unroll
    for (int q = 0; q < 4; ++q) {
        int f = q * 256 + tid;
        int m = f >> 5;
        int k = (f & 31) * 4;
        int node = n0 + m;
        float4 av = {0.f, 0.f, 0.f, 0.f}, hv = {0.f, 0.f, 0.f, 0.f};
        if (node < N_NODES) {
            float inv = invdeg[node];
            av = *(const float4*)(agg + (size_t)node * HID + k);
            av.x *= inv; av.y *= inv; av.z *= inv; av.w *= inv;
            hv = *(const float4*)(hn + (size_t)node * HID + k);
        }
        *(float4*)&s_a[m * HID + k] = av;
        *(float4*)&s_h[m * HID + k] = hv;
    }
    __syncthreads();

    int jj = tid & 63;        // j0 = 2*jj, j1 = 2*jj+1
    int grp = tid >> 6;       // wave id: 8 nodes per wave
    const float2* Wl2 = (const float2*)Wl;
    const float2* Wr2 = (const float2*)Wr;
    float acc0[8], acc1[8];
    #pragma unroll
    for (int m = 0; m < 8; ++m) { acc0[m] = 0.f; acc1[m] = 0.f; }

    for (int k4 = 0; k4 < 32; ++k4) {
        float2 wl[4], wr[4];
        #pragma unroll
        for (int t = 0; t < 4; ++t) {
            wl[t] = Wl2[(k4 * 4 + t) * 64 + jj];
            wr[t] = Wr2[(k4 * 4 + t) * 64 + jj];
        }
        #pragma unroll
        for (int m = 0; m < 8; ++m) {
            const float4 a  = *(const float4*)&s_a[(grp * 8 + m) * HID + k4 * 4];
            const float4 hh = *(const float4*)&s_h[(grp * 8 + m) * HID + k4 * 4];
            acc0[m] += a.x * wl[0].x + a.y * wl[1].x + a.z * wl[2].x + a.w * wl[3].x
                     + hh.x * wr[0].x + hh.y * wr[1].x + hh.z * wr[2].x + hh.w * wr[3].x;
            acc1[m] += a.x * wl[0].y + a.y * wl[1].y + a.z * wl[2].y + a.w * wl[3].y
                     + hh.x * wr[0].y + hh.y * wr[1].y + hh.z * wr[2].y + hh.w * wr[3].y;
        }
    }

    int j0 = jj * 2;
    float bl0 = bl[j0], bl1 = bl[j0 + 1];
    #pragma unroll
    for (int m = 0; m < 8; ++m) {
        int node = n0 + grp * 8 + m;
        if (node >= N_NODES) continue;
        const float2 hr = *(const float2*)(hres + (size_t)node * HID + j0);
        float2 o;
        o.x = fmaxf(hr.x + acc0[m] + bl0, 0.f);
        o.y = fmaxf(hr.y + acc1[m] + bl1, 0.f);
        *(float2*)(hout + (size_t)node * HID + j0) = o;
    }
}

// ---- out = h @ W_out + b_out ----
__global__ void out_proj_kernel(const float* __restrict__ h, const float* __restrict__ W,
                                const float* __restrict__ b, float* __restrict__ out) {
    int t = blockIdx.x * 256 + threadIdx.x;
    if (t >= N_NODES * D_OUT) return;
    int n = t >> 2, d = t & 3;
    float acc = b[d];
    const float* hr = h + (size_t)n * HID;
    #pragma unroll 4
    for (int k = 0; k < HID; ++k) acc += hr[k] * W[k * D_OUT + d];
    out[t] = acc;
}

extern "C" void kernel_launch(void* const* d_in, const int* in_sizes, int n_in,
                              void* d_out, int out_size, void* d_ws, size_t ws_size,
                              hipStream_t stream) {
    const float* x    = (const float*)d_in[0];
    const int*   ei   = (const int*)d_in[1];
    const float* W_in = (const float*)d_in[2];
    const float* b_in = (const float*)d_in[3];
    const float* Wl   = (const float*)d_in[4];
    const float* bl   = (const float*)d_in[5];
    const float* Wr   = (const float*)d_in[6];
    const float* ln_g = (const float*)d_in[7];
    const float* ln_b = (const float*)d_in[8];
    const float* W_out= (const float*)d_in[9];
    const float* b_out= (const float*)d_in[10];
    float* out = (float*)d_out;

    float* ws  = (float*)d_ws;
    float* h   = ws;                                   // 6.4M floats
    float* hn  = h   + (size_t)N_NODES * HID;          // 6.4M
    float* agg = hn  + (size_t)N_NODES * HID;          // 6.4M
    float* deg = agg + (size_t)N_NODES * HID;          // 50K (becomes inv_deg)

    const int* src = ei;
    const int* dst = ei + N_EDGES;

    hipMemsetAsync(deg, 0, N_NODES * sizeof(float), stream);
    deg_kernel<<<(N_EDGES + 255) / 256, 256, 0, stream>>>(dst, deg);
    invdeg_kernel<<<(N_NODES + 255) / 256, 256, 0, stream>>>(deg);

    in_proj_kernel<<<(N_NODES + 1) / 2, 256, 0, stream>>>(x, W_in, b_in, h);

    for (int i = 0; i < N_LAYERS; ++i) {
        ln_kernel<<<(N_NODES + 3) / 4, 256, 0, stream>>>(h, ln_g + i * HID, ln_b + i * HID, hn);
        hipMemsetAsync(agg, 0, (size_t)N_NODES * HID * sizeof(float), stream);
        scatter_kernel<<<(N_EDGES * 32 + 255) / 256, 256, 0, stream>>>(src, dst, hn, agg);
        conv_kernel<<<(N_NODES + 31) / 32, 256, 0, stream>>>(
            h, hn, agg, deg, Wl + (size_t)i * HID * HID, bl + i * HID,
            Wr + (size_t)i * HID * HID, h);
    }

    out_proj_kernel<<<(N_NODES * D_OUT + 255) / 256, 256, 0, stream>>>(h, W_out, b_out, out);
}

// Round 2
// 758.747 us; speedup vs baseline: 5.9132x; 5.9132x over previous
//
#include <hip/hip_runtime.h>

#define N_NODES 50000
#define N_EDGES 800000
#define D_IN 16
#define HID 128
#define D_OUT 4
#define N_LAYERS 3
#define LN_EPS 1e-5f

// ---- int degree count ----
__global__ void degi_kernel(const int* __restrict__ dst, int* __restrict__ deg) {
    int e = blockIdx.x * 256 + threadIdx.x;
    if (e < N_EDGES) atomicAdd(&deg[dst[e]], 1);
}

// ---- exclusive scan of degrees -> rowptr, plus invdeg ----
__global__ __launch_bounds__(1024) void scan_kernel(const int* __restrict__ deg,
        int* __restrict__ rowptr, float* __restrict__ invdeg) {
    __shared__ int s_sum[1024];
    int t = threadIdx.x;
    const int chunk = (N_NODES + 1023) / 1024;   // 49
    int base = t * chunk;
    int lsum = 0;
    for (int i = 0; i < chunk; ++i) {
        int idx = base + i;
        if (idx < N_NODES) lsum += deg[idx];
    }
    s_sum[t] = lsum;
    __syncthreads();
    for (int off = 1; off < 1024; off <<= 1) {
        int v = (t >= off) ? s_sum[t - off] : 0;
        __syncthreads();
        s_sum[t] += v;
        __syncthreads();
    }
    int run = (t == 0) ? 0 : s_sum[t - 1];
    for (int i = 0; i < chunk; ++i) {
        int idx = base + i;
        if (idx < N_NODES) {
            rowptr[idx] = run;
            int d = deg[idx];
            run += d;
            invdeg[idx] = 1.0f / fmaxf((float)d, 1.0f);
        }
    }
    if (t == 1023) rowptr[N_NODES] = run;        // == N_EDGES
}

// ---- CSR fill ----
__global__ void fill_kernel(const int* __restrict__ src, const int* __restrict__ dst,
                            const int* __restrict__ rowptr, int* __restrict__ cursor,
                            int* __restrict__ csr_src) {
    int e = blockIdx.x * 256 + threadIdx.x;
    if (e >= N_EDGES) return;
    int d = dst[e];
    int pos = rowptr[d] + atomicAdd(&cursor[d], 1);
    csr_src[pos] = src[e];
}

// ---- h = x @ W_in + b_in ----
__global__ void in_proj_kernel(const float* __restrict__ x, const float* __restrict__ W,
                               const float* __restrict__ b, float* __restrict__ h) {
    int node = blockIdx.x * 2 + (threadIdx.x >> 7);
    int j = threadIdx.x & 127;
    if (node >= N_NODES) return;
    float acc = b[j];
    #pragma unroll
    for (int k = 0; k < D_IN; ++k) acc += x[node * D_IN + k] * W[k * HID + j];
    h[node * HID + j] = acc;
}

// ---- hn = LN(h)*g + b : one wave per node ----
__global__ void ln_kernel(const float* __restrict__ h, const float* __restrict__ g,
                          const float* __restrict__ b, float* __restrict__ hn) {
    int wave = threadIdx.x >> 6;
    int lane = threadIdx.x & 63;
    int node = blockIdx.x * 4 + wave;
    if (node >= N_NODES) return;
    const float* hr = h + (size_t)node * HID;
    float v0 = hr[lane], v1 = hr[lane + 64];
    float s = v0 + v1;
    #pragma unroll
    for (int o = 32; o > 0; o >>= 1) s += __shfl_xor(s, o, 64);
    float mu = s * (1.0f / HID);
    float d0 = v0 - mu, d1 = v1 - mu;
    float q = d0 * d0 + d1 * d1;
    #pragma unroll
    for (int o = 32; o > 0; o >>= 1) q += __shfl_xor(q, o, 64);
    float rstd = rsqrtf(q * (1.0f / HID) + LN_EPS);
    hn[(size_t)node * HID + lane]      = d0 * rstd * g[lane]      + b[lane];
    hn[(size_t)node * HID + lane + 64] = d1 * rstd * g[lane + 64] + b[lane + 64];
}

// ---- agg[n] = invdeg[n] * sum_{e in CSR[n]} hn[src[e]] : one wave per node ----
__global__ __launch_bounds__(256) void gather_kernel(
        const int* __restrict__ rowptr, const int* __restrict__ csr_src,
        const float* __restrict__ hn, const float* __restrict__ invdeg,
        float* __restrict__ agg) {
    int wave = threadIdx.x >> 6, lane = threadIdx.x & 63;
    int node = blockIdx.x * 4 + wave;
    if (node >= N_NODES) return;
    int beg = rowptr[node], end = rowptr[node + 1];
    float2 acc = {0.f, 0.f};
    const float* basep = hn + lane * 2;
    int i = beg;
    for (; i + 4 <= end; i += 4) {          // 4-deep MLP for latency hiding
        int s0 = csr_src[i], s1 = csr_src[i + 1], s2 = csr_src[i + 2], s3 = csr_src[i + 3];
        float2 v0 = *(const float2*)(basep + (size_t)s0 * HID);
        float2 v1 = *(const float2*)(basep + (size_t)s1 * HID);
        float2 v2 = *(const float2*)(basep + (size_t)s2 * HID);
        float2 v3 = *(const float2*)(basep + (size_t)s3 * HID);
        acc.x += (v0.x + v1.x) + (v2.x + v3.x);
        acc.y += (v0.y + v1.y) + (v2.y + v3.y);
    }
    for (; i < end; ++i) {
        int s = csr_src[i];
        float2 v = *(const float2*)(basep + (size_t)s * HID);
        acc.x += v.x; acc.y += v.y;
    }
    float inv = invdeg[node];
    float2 o; o.x = acc.x * inv; o.y = acc.y * inv;
    *(float2*)(agg + (size_t)node * HID + lane * 2) = o;
}

// ---- h = relu(h + agg@Wl + bl + hn@Wr) : 32-node tile, fp32 (agg pre-normalized) ----
__global__ __launch_bounds__(256) void conv_kernel(
    const float* __restrict__ hres, const float* __restrict__ hn,
    const float* __restrict__ agg,
    const float* __restrict__ Wl, const float* __restrict__ bl,
    const float* __restrict__ Wr, float* __restrict__ hout) {
    __shared__ float s_a[32 * HID];
    __shared__ float s_h[32 * HID];
    int tid = threadIdx.x;
    int n0 = blockIdx.x * 32;

    #pragma unroll
    for (int q = 0; q < 4; ++q) {
        int f = q * 256 + tid;
        int m = f >> 5;
        int k = (f & 31) * 4;
        int node = n0 + m;
        float4 av = {0.f, 0.f, 0.f, 0.f}, hv = {0.f, 0.f, 0.f, 0.f};
        if (node < N_NODES) {
            av = *(const float4*)(agg + (size_t)node * HID + k);
            hv = *(const float4*)(hn + (size_t)node * HID + k);
        }
        *(float4*)&s_a[m * HID + k] = av;
        *(float4*)&s_h[m * HID + k] = hv;
    }
    __syncthreads();

    int jj = tid & 63;        // j0 = 2*jj, j1 = 2*jj+1
    int grp = tid >> 6;       // wave id: 8 nodes per wave
    const float2* Wl2 = (const float2*)Wl;
    const float2* Wr2 = (const float2*)Wr;
    float acc0[8], acc1[8];
    #pragma unroll
    for (int m = 0; m < 8; ++m) { acc0[m] = 0.f; acc1[m] = 0.f; }

    for (int k4 = 0; k4 < 32; ++k4) {
        float2 wl[4], wr[4];
        #pragma unroll
        for (int t = 0; t < 4; ++t) {
            wl[t] = Wl2[(k4 * 4 + t) * 64 + jj];
            wr[t] = Wr2[(k4 * 4 + t) * 64 + jj];
        }
        #pragma unroll
        for (int m = 0; m < 8; ++m) {
            const float4 a  = *(const float4*)&s_a[(grp * 8 + m) * HID + k4 * 4];
            const float4 hh = *(const float4*)&s_h[(grp * 8 + m) * HID + k4 * 4];
            acc0[m] += a.x * wl[0].x + a.y * wl[1].x + a.z * wl[2].x + a.w * wl[3].x
                     + hh.x * wr[0].x + hh.y * wr[1].x + hh.z * wr[2].x + hh.w * wr[3].x;
            acc1[m] += a.x * wl[0].y + a.y * wl[1].y + a.z * wl[2].y + a.w * wl[3].y
                     + hh.x * wr[0].y + hh.y * wr[1].y + hh.z * wr[2].y + hh.w * wr[3].y;
        }
    }

    int j0 = jj * 2;
    float bl0 = bl[j0], bl1 = bl[j0 + 1];
    #pragma unroll
    for (int m = 0; m < 8; ++m) {
        int node = n0 + grp * 8 + m;
        if (node >= N_NODES) continue;
        const float2 hr = *(const float2*)(hres + (size_t)node * HID + j0);
        float2 o;
        o.x = fmaxf(hr.x + acc0[m] + bl0, 0.f);
        o.y = fmaxf(hr.y + acc1[m] + bl1, 0.f);
        *(float2*)(hout + (size_t)node * HID + j0) = o;
    }
}

// ---- out = h @ W_out + b_out ----
__global__ void out_proj_kernel(const float* __restrict__ h, const float* __restrict__ W,
                                const float* __restrict__ b, float* __restrict__ out) {
    int t = blockIdx.x * 256 + threadIdx.x;
    if (t >= N_NODES * D_OUT) return;
    int n = t >> 2, d = t & 3;
    float acc = b[d];
    const float* hr = h + (size_t)n * HID;
    #pragma unroll 4
    for (int k = 0; k < HID; ++k) acc += hr[k] * W[k * D_OUT + d];
    out[t] = acc;
}

extern "C" void kernel_launch(void* const* d_in, const int* in_sizes, int n_in,
                              void* d_out, int out_size, void* d_ws, size_t ws_size,
                              hipStream_t stream) {
    const float* x    = (const float*)d_in[0];
    const int*   ei   = (const int*)d_in[1];
    const float* W_in = (const float*)d_in[2];
    const float* b_in = (const float*)d_in[3];
    const float* Wl   = (const float*)d_in[4];
    const float* bl   = (const float*)d_in[5];
    const float* Wr   = (const float*)d_in[6];
    const float* ln_g = (const float*)d_in[7];
    const float* ln_b = (const float*)d_in[8];
    const float* W_out= (const float*)d_in[9];
    const float* b_out= (const float*)d_in[10];
    float* out = (float*)d_out;

    float* ws  = (float*)d_ws;
    float* h      = ws;                                   // 6.4M floats
    float* hn     = h   + (size_t)N_NODES * HID;          // 6.4M
    float* agg    = hn  + (size_t)N_NODES * HID;          // 6.4M
    float* invdeg = agg + (size_t)N_NODES * HID;          // 50K
    int*   degi   = (int*)(invdeg + N_NODES);             // 50K ints
    int*   rowptr = degi + N_NODES;                       // 50K+1 ints
    int*   cursor = rowptr + (N_NODES + 1);               // 50K ints
    int*   csr_src= cursor + N_NODES;                     // 800K ints

    const int* src = ei;
    const int* dst = ei + N_EDGES;

    // ---- CSR build (once, reused across layers) ----
    hipMemsetAsync(degi, 0, N_NODES * sizeof(int), stream);
    hipMemsetAsync(cursor, 0, N_NODES * sizeof(int), stream);
    degi_kernel<<<(N_EDGES + 255) / 256, 256, 0, stream>>>(dst, degi);
    scan_kernel<<<1, 1024, 0, stream>>>(degi, rowptr, invdeg);
    fill_kernel<<<(N_EDGES + 255) / 256, 256, 0, stream>>>(src, dst, rowptr, cursor, csr_src);

    in_proj_kernel<<<(N_NODES + 1) / 2, 256, 0, stream>>>(x, W_in, b_in, h);

    for (int i = 0; i < N_LAYERS; ++i) {
        ln_kernel<<<(N_NODES + 3) / 4, 256, 0, stream>>>(h, ln_g + i * HID, ln_b + i * HID, hn);
        gather_kernel<<<(N_NODES + 3) / 4, 256, 0, stream>>>(rowptr, csr_src, hn, invdeg, agg);
        conv_kernel<<<(N_NODES + 31) / 32, 256, 0, stream>>>(
            h, hn, agg, Wl + (size_t)i * HID * HID, bl + i * HID,
            Wr + (size_t)i * HID * HID, h);
    }

    out_proj_kernel<<<(N_NODES * D_OUT + 255) / 256, 256, 0, stream>>>(h, W_out, b_out, out);
}

// Round 3
// 645.744 us; speedup vs baseline: 6.9480x; 1.1750x over previous
//
#include <hip/hip_runtime.h>

#define N_NODES 50000
#define N_EDGES 800000
#define D_IN 16
#define HID 128
#define D_OUT 4
#define N_LAYERS 3
#define LN_EPS 1e-5f
#define SCAN_BLOCKS ((N_NODES + 255) / 256)   // 196

// ---- int degree count ----
__global__ void degi_kernel(const int* __restrict__ dst, int* __restrict__ deg) {
    int e = blockIdx.x * 256 + threadIdx.x;
    if (e < N_EDGES) atomicAdd(&deg[dst[e]], 1);
}

// ---- hierarchical exclusive scan: per-block sums ----
__global__ __launch_bounds__(256) void blocksum_kernel(const int* __restrict__ deg,
                                                       int* __restrict__ bs) {
    __shared__ int red[256];
    int t = threadIdx.x;
    int n = blockIdx.x * 256 + t;
    red[t] = (n < N_NODES) ? deg[n] : 0;
    __syncthreads();
    for (int off = 128; off > 0; off >>= 1) {
        if (t < off) red[t] += red[t + off];
        __syncthreads();
    }
    if (t == 0) bs[blockIdx.x] = red[0];
}

// ---- scan the 196 block sums (1 small block) ----
__global__ __launch_bounds__(256) void scanbs_kernel(const int* __restrict__ bs,
                                                     int* __restrict__ boff) {
    __shared__ int s[256];
    int t = threadIdx.x;
    s[t] = (t < SCAN_BLOCKS) ? bs[t] : 0;
    __syncthreads();
    for (int off = 1; off < 256; off <<= 1) {
        int u = (t >= off) ? s[t - off] : 0;
        __syncthreads();
        s[t] += u;
        __syncthreads();
    }
    boff[t] = (t == 0) ? 0 : s[t - 1];   // exclusive
}

// ---- rowptr + invdeg from block offsets ----
__global__ __launch_bounds__(256) void rowptr_kernel(const int* __restrict__ deg,
        const int* __restrict__ boff, int* __restrict__ rowptr, float* __restrict__ invdeg) {
    __shared__ int s[256];
    int t = threadIdx.x;
    int n = blockIdx.x * 256 + t;
    int v = (n < N_NODES) ? deg[n] : 0;
    s[t] = v;
    __syncthreads();
    for (int off = 1; off < 256; off <<= 1) {    // inclusive scan
        int u = (t >= off) ? s[t - off] : 0;
        __syncthreads();
        s[t] += u;
        __syncthreads();
    }
    if (n < N_NODES) {
        rowptr[n] = s[t] - v + boff[blockIdx.x];
        invdeg[n] = 1.0f / fmaxf((float)v, 1.0f);
    }
    if (n == N_NODES - 1) rowptr[N_NODES] = s[t] + boff[blockIdx.x];
}

// ---- CSR fill ----
__global__ void fill_kernel(const int* __restrict__ src, const int* __restrict__ dst,
                            const int* __restrict__ rowptr, int* __restrict__ cursor,
                            int* __restrict__ csr_src) {
    int e = blockIdx.x * 256 + threadIdx.x;
    if (e >= N_EDGES) return;
    int d = dst[e];
    int pos = rowptr[d] + atomicAdd(&cursor[d], 1);
    csr_src[pos] = src[e];
}

// ---- h = x @ W_in + b_in, fused with first LayerNorm. One wave per node. ----
__global__ __launch_bounds__(256) void in_proj_ln_kernel(
        const float* __restrict__ x, const float* __restrict__ W, const float* __restrict__ b,
        const float* __restrict__ g0, const float* __restrict__ bb0,
        float* __restrict__ h, float* __restrict__ hn) {
    int wave = threadIdx.x >> 6, lane = threadIdx.x & 63;
    int node = blockIdx.x * 4 + wave;
    if (node >= N_NODES) return;
    int j0 = lane * 2;
    float a0 = b[j0], a1 = b[j0 + 1];
    const float* xr = x + (size_t)node * D_IN;
    #pragma unroll
    for (int k = 0; k < D_IN; ++k) {
        float xv = xr[k];
        float2 w = *(const float2*)(W + k * HID + j0);
        a0 += xv * w.x;
        a1 += xv * w.y;
    }
    float2 hv; hv.x = a0; hv.y = a1;
    *(float2*)(h + (size_t)node * HID + j0) = hv;
    float s = a0 + a1;
    #pragma unroll
    for (int o = 32; o > 0; o >>= 1) s += __shfl_xor(s, o, 64);
    float mu = s * (1.0f / HID);
    float d0 = a0 - mu, d1 = a1 - mu;
    float q = d0 * d0 + d1 * d1;
    #pragma unroll
    for (int o = 32; o > 0; o >>= 1) q += __shfl_xor(q, o, 64);
    float rstd = rsqrtf(q * (1.0f / HID) + LN_EPS);
    float2 gg = *(const float2*)(g0 + j0);
    float2 bb = *(const float2*)(bb0 + j0);
    float2 o2; o2.x = d0 * rstd * gg.x + bb.x; o2.y = d1 * rstd * gg.y + bb.y;
    *(float2*)(hn + (size_t)node * HID + j0) = o2;
}

// ---- agg[n] = invdeg[n] * sum_{e in CSR[n]} hn[src[e]] : one wave per node ----
__global__ __launch_bounds__(256) void gather_kernel(
        const int* __restrict__ rowptr, const int* __restrict__ csr_src,
        const float* __restrict__ hn, const float* __restrict__ invdeg,
        float* __restrict__ agg) {
    int wave = threadIdx.x >> 6, lane = threadIdx.x & 63;
    int node = blockIdx.x * 4 + wave;
    if (node >= N_NODES) return;
    int beg = rowptr[node], end = rowptr[node + 1];
    float2 acc = {0.f, 0.f};
    const float* basep = hn + lane * 2;
    int i = beg;
    for (; i + 4 <= end; i += 4) {
        int s0 = csr_src[i], s1 = csr_src[i + 1], s2 = csr_src[i + 2], s3 = csr_src[i + 3];
        float2 v0 = *(const float2*)(basep + (size_t)s0 * HID);
        float2 v1 = *(const float2*)(basep + (size_t)s1 * HID);
        float2 v2 = *(const float2*)(basep + (size_t)s2 * HID);
        float2 v3 = *(const float2*)(basep + (size_t)s3 * HID);
        acc.x += (v0.x + v1.x) + (v2.x + v3.x);
        acc.y += (v0.y + v1.y) + (v2.y + v3.y);
    }
    for (; i < end; ++i) {
        int s = csr_src[i];
        float2 v = *(const float2*)(basep + (size_t)s * HID);
        acc.x += v.x; acc.y += v.y;
    }
    float inv = invdeg[node];
    float2 o; o.x = acc.x * inv; o.y = acc.y * inv;
    *(float2*)(agg + (size_t)node * HID + lane * 2) = o;
}

// ---- h = relu(h + agg@Wl + bl + hn@Wr), fused next-layer LN -> hn (in place) ----
__global__ __launch_bounds__(256) void conv_kernel(
    const float* __restrict__ hres, float* __restrict__ hn,
    const float* __restrict__ agg,
    const float* __restrict__ Wl, const float* __restrict__ bl,
    const float* __restrict__ Wr, float* __restrict__ hout,
    const float* __restrict__ lng, const float* __restrict__ lnb, int do_ln) {
    __shared__ float s_a[32 * HID];
    __shared__ float s_h[32 * HID];
    int tid = threadIdx.x;
    int n0 = blockIdx.x * 32;

    #pragma unroll
    for (int q = 0; q < 4; ++q) {
        int f = q * 256 + tid;
        int m = f >> 5;
        int k = (f & 31) * 4;
        int node = n0 + m;
        float4 av = {0.f, 0.f, 0.f, 0.f}, hv = {0.f, 0.f, 0.f, 0.f};
        if (node < N_NODES) {
            av = *(const float4*)(agg + (size_t)node * HID + k);
            hv = *(const float4*)(hn + (size_t)node * HID + k);
        }
        *(float4*)&s_a[m * HID + k] = av;
        *(float4*)&s_h[m * HID + k] = hv;
    }
    __syncthreads();

    int jj = tid & 63;        // j0 = 2*jj, j1 = 2*jj+1
    int grp = tid >> 6;       // wave id: 8 nodes per wave
    const float2* Wl2 = (const float2*)Wl;
    const float2* Wr2 = (const float2*)Wr;
    float acc0[8], acc1[8];
    #pragma unroll
    for (int m = 0; m < 8; ++m) { acc0[m] = 0.f; acc1[m] = 0.f; }

    for (int k4 = 0; k4 < 32; ++k4) {
        float2 wl[4], wr[4];
        #pragma unroll
        for (int t = 0; t < 4; ++t) {
            wl[t] = Wl2[(k4 * 4 + t) * 64 + jj];
            wr[t] = Wr2[(k4 * 4 + t) * 64 + jj];
        }
        #pragma unroll
        for (int m = 0; m < 8; ++m) {
            const float4 a  = *(const float4*)&s_a[(grp * 8 + m) * HID + k4 * 4];
            const float4 hh = *(const float4*)&s_h[(grp * 8 + m) * HID + k4 * 4];
            acc0[m] += a.x * wl[0].x + a.y * wl[1].x + a.z * wl[2].x + a.w * wl[3].x
                     + hh.x * wr[0].x + hh.y * wr[1].x + hh.z * wr[2].x + hh.w * wr[3].x;
            acc1[m] += a.x * wl[0].y + a.y * wl[1].y + a.z * wl[2].y + a.w * wl[3].y
                     + hh.x * wr[0].y + hh.y * wr[1].y + hh.z * wr[2].y + hh.w * wr[3].y;
        }
    }

    int j0 = jj * 2;
    float bl0 = bl[j0], bl1 = bl[j0 + 1];
    float2 gg = {0.f, 0.f}, bb = {0.f, 0.f};
    if (do_ln) {
        gg = *(const float2*)(lng + j0);
        bb = *(const float2*)(lnb + j0);
    }
    #pragma unroll
    for (int m = 0; m < 8; ++m) {
        int node = n0 + grp * 8 + m;       // wave-uniform
        if (node >= N_NODES) continue;
        const float2 hr = *(const float2*)(hres + (size_t)node * HID + j0);
        float ox = fmaxf(hr.x + acc0[m] + bl0, 0.f);
        float oy = fmaxf(hr.y + acc1[m] + bl1, 0.f);
        float2 o; o.x = ox; o.y = oy;
        *(float2*)(hout + (size_t)node * HID + j0) = o;
        if (do_ln) {
            float s = ox + oy;
            #pragma unroll
            for (int of = 32; of > 0; of >>= 1) s += __shfl_xor(s, of, 64);
            float mu = s * (1.0f / HID);
            float dx = ox - mu, dy = oy - mu;
            float q = dx * dx + dy * dy;
            #pragma unroll
            for (int of = 32; of > 0; of >>= 1) q += __shfl_xor(q, of, 64);
            float rstd = rsqrtf(q * (1.0f / HID) + LN_EPS);
            float2 hno;
            hno.x = dx * rstd * gg.x + bb.x;
            hno.y = dy * rstd * gg.y + bb.y;
            *(float2*)(hn + (size_t)node * HID + j0) = hno;
        }
    }
}

// ---- out = h @ W_out + b_out ----
__global__ void out_proj_kernel(const float* __restrict__ h, const float* __restrict__ W,
                                const float* __restrict__ b, float* __restrict__ out) {
    int t = blockIdx.x * 256 + threadIdx.x;
    if (t >= N_NODES * D_OUT) return;
    int n = t >> 2, d = t & 3;
    float acc = b[d];
    const float* hr = h + (size_t)n * HID;
    #pragma unroll 4
    for (int k = 0; k < HID; ++k) acc += hr[k] * W[k * D_OUT + d];
    out[t] = acc;
}

extern "C" void kernel_launch(void* const* d_in, const int* in_sizes, int n_in,
                              void* d_out, int out_size, void* d_ws, size_t ws_size,
                              hipStream_t stream) {
    const float* x    = (const float*)d_in[0];
    const int*   ei   = (const int*)d_in[1];
    const float* W_in = (const float*)d_in[2];
    const float* b_in = (const float*)d_in[3];
    const float* Wl   = (const float*)d_in[4];
    const float* bl   = (const float*)d_in[5];
    const float* Wr   = (const float*)d_in[6];
    const float* ln_g = (const float*)d_in[7];
    const float* ln_b = (const float*)d_in[8];
    const float* W_out= (const float*)d_in[9];
    const float* b_out= (const float*)d_in[10];
    float* out = (float*)d_out;

    float* ws  = (float*)d_ws;
    float* h      = ws;                                   // 6.4M floats
    float* hn     = h   + (size_t)N_NODES * HID;          // 6.4M
    float* agg    = hn  + (size_t)N_NODES * HID;          // 6.4M
    float* invdeg = agg + (size_t)N_NODES * HID;          // 50K
    int*   degi   = (int*)(invdeg + N_NODES);             // 50K ints
    int*   rowptr = degi + N_NODES;                       // 50K+1 ints
    int*   cursor = rowptr + (N_NODES + 1);               // 50K ints
    int*   csr_src= cursor + N_NODES;                     // 800K ints
    int*   bs     = csr_src + N_EDGES;                    // 196
    int*   boff   = bs + 256;                             // 256

    const int* src = ei;
    const int* dst = ei + N_EDGES;

    // ---- CSR build (once, reused across layers) ----
    hipMemsetAsync(degi, 0, N_NODES * sizeof(int), stream);
    hipMemsetAsync(cursor, 0, N_NODES * sizeof(int), stream);
    degi_kernel<<<(N_EDGES + 255) / 256, 256, 0, stream>>>(dst, degi);
    blocksum_kernel<<<SCAN_BLOCKS, 256, 0, stream>>>(degi, bs);
    scanbs_kernel<<<1, 256, 0, stream>>>(bs, boff);
    rowptr_kernel<<<SCAN_BLOCKS, 256, 0, stream>>>(degi, boff, rowptr, invdeg);
    fill_kernel<<<(N_EDGES + 255) / 256, 256, 0, stream>>>(src, dst, rowptr, cursor, csr_src);

    in_proj_ln_kernel<<<(N_NODES + 3) / 4, 256, 0, stream>>>(
        x, W_in, b_in, ln_g, ln_b, h, hn);

    for (int i = 0; i < N_LAYERS; ++i) {
        gather_kernel<<<(N_NODES + 3) / 4, 256, 0, stream>>>(rowptr, csr_src, hn, invdeg, agg);
        int do_ln = (i + 1 < N_LAYERS) ? 1 : 0;
        const float* g_next = ln_g + (do_ln ? (size_t)(i + 1) * HID : 0);
        const float* b_next = ln_b + (do_ln ? (size_t)(i + 1) * HID : 0);
        conv_kernel<<<(N_NODES + 31) / 32, 256, 0, stream>>>(
            h, hn, agg, Wl + (size_t)i * HID * HID, bl + i * HID,
            Wr + (size_t)i * HID * HID, h, g_next, b_next, do_ln);
    }

    out_proj_kernel<<<(N_NODES * D_OUT + 255) / 256, 256, 0, stream>>>(h, W_out, b_out, out);
}

// Round 4
// 390.070 us; speedup vs baseline: 11.5022x; 1.6555x over previous
//
#include <hip/hip_runtime.h>

#define N_NODES 50000
#define N_EDGES 800000
#define D_IN 16
#define HID 128
#define D_OUT 4
#define N_LAYERS 3
#define LN_EPS 1e-5f
#define SCAN_BLOCKS ((N_NODES + 255) / 256)   // 196

typedef __attribute__((ext_vector_type(8))) short bf16x8;
typedef __attribute__((ext_vector_type(4))) float f32x4;

__device__ __forceinline__ unsigned short f2bf(float f) {
    union { float f; unsigned int u; } a; a.f = f;
    unsigned int r = a.u + 0x7fffu + ((a.u >> 16) & 1u);   // RNE
    return (unsigned short)(r >> 16);
}
__device__ __forceinline__ float bf_lo(unsigned int u) {
    union { unsigned int u; float f; } c; c.u = u << 16; return c.f;
}
__device__ __forceinline__ float bf_hi(unsigned int u) {
    union { unsigned int u; float f; } c; c.u = u & 0xffff0000u; return c.f;
}

// ---- int degree count ----
__global__ void degi_kernel(const int* __restrict__ dst, int* __restrict__ deg) {
    int e = blockIdx.x * 256 + threadIdx.x;
    if (e < N_EDGES) atomicAdd(&deg[dst[e]], 1);
}

// ---- hierarchical exclusive scan: per-block sums ----
__global__ __launch_bounds__(256) void blocksum_kernel(const int* __restrict__ deg,
                                                       int* __restrict__ bs) {
    __shared__ int red[256];
    int t = threadIdx.x;
    int n = blockIdx.x * 256 + t;
    red[t] = (n < N_NODES) ? deg[n] : 0;
    __syncthreads();
    for (int off = 128; off > 0; off >>= 1) {
        if (t < off) red[t] += red[t + off];
        __syncthreads();
    }
    if (t == 0) bs[blockIdx.x] = red[0];
}

__global__ __launch_bounds__(256) void scanbs_kernel(const int* __restrict__ bs,
                                                     int* __restrict__ boff) {
    __shared__ int s[256];
    int t = threadIdx.x;
    s[t] = (t < SCAN_BLOCKS) ? bs[t] : 0;
    __syncthreads();
    for (int off = 1; off < 256; off <<= 1) {
        int u = (t >= off) ? s[t - off] : 0;
        __syncthreads();
        s[t] += u;
        __syncthreads();
    }
    boff[t] = (t == 0) ? 0 : s[t - 1];   // exclusive
}

__global__ __launch_bounds__(256) void rowptr_kernel(const int* __restrict__ deg,
        const int* __restrict__ boff, int* __restrict__ rowptr, float* __restrict__ invdeg) {
    __shared__ int s[256];
    int t = threadIdx.x;
    int n = blockIdx.x * 256 + t;
    int v = (n < N_NODES) ? deg[n] : 0;
    s[t] = v;
    __syncthreads();
    for (int off = 1; off < 256; off <<= 1) {    // inclusive scan
        int u = (t >= off) ? s[t - off] : 0;
        __syncthreads();
        s[t] += u;
        __syncthreads();
    }
    if (n < N_NODES) {
        rowptr[n] = s[t] - v + boff[blockIdx.x];
        invdeg[n] = 1.0f / fmaxf((float)v, 1.0f);
    }
    if (n == N_NODES - 1) rowptr[N_NODES] = s[t] + boff[blockIdx.x];
}

// ---- CSR fill ----
__global__ void fill_kernel(const int* __restrict__ src, const int* __restrict__ dst,
                            const int* __restrict__ rowptr, int* __restrict__ cursor,
                            int* __restrict__ csr_src) {
    int e = blockIdx.x * 256 + threadIdx.x;
    if (e >= N_EDGES) return;
    int d = dst[e];
    int pos = rowptr[d] + atomicAdd(&cursor[d], 1);
    csr_src[pos] = src[e];
}

// ---- weights: BT[i][n][k] = bf16( k<128 ? Wl[i][k][n] : Wr[i][k-128][n] ) ----
__global__ __launch_bounds__(256) void wprep_kernel(const float* __restrict__ Wl,
        const float* __restrict__ Wr, unsigned short* __restrict__ BT) {
    int bx = blockIdx.x;              // 3*128
    int i = bx >> 7, n = bx & 127;
    int k = threadIdx.x;              // 0..255
    float v = (k < 128) ? Wl[((size_t)i * 128 + k) * 128 + n]
                        : Wr[((size_t)i * 128 + (k - 128)) * 128 + n];
    BT[((size_t)i * 128 + n) * 256 + k] = f2bf(v);
}

// ---- h = x @ W_in + b_in, fused first LayerNorm -> ahn hn-half (bf16) ----
__global__ __launch_bounds__(256) void in_proj_ln_kernel(
        const float* __restrict__ x, const float* __restrict__ W, const float* __restrict__ b,
        const float* __restrict__ g0, const float* __restrict__ bb0,
        float* __restrict__ h, unsigned short* __restrict__ ahn) {
    int wave = threadIdx.x >> 6, lane = threadIdx.x & 63;
    int node = blockIdx.x * 4 + wave;
    if (node >= N_NODES) return;
    int j0 = lane * 2;
    float a0 = b[j0], a1 = b[j0 + 1];
    const float* xr = x + (size_t)node * D_IN;
    #pragma unroll
    for (int k = 0; k < D_IN; ++k) {
        float xv = xr[k];
        float2 w = *(const float2*)(W + k * HID + j0);
        a0 += xv * w.x;
        a1 += xv * w.y;
    }
    float2 hv; hv.x = a0; hv.y = a1;
    *(float2*)(h + (size_t)node * HID + j0) = hv;
    float s = a0 + a1;
    #pragma unroll
    for (int o = 32; o > 0; o >>= 1) s += __shfl_xor(s, o, 64);
    float mu = s * (1.0f / HID);
    float d0 = a0 - mu, d1 = a1 - mu;
    float q = d0 * d0 + d1 * d1;
    #pragma unroll
    for (int o = 32; o > 0; o >>= 1) q += __shfl_xor(q, o, 64);
    float rstd = rsqrtf(q * (1.0f / HID) + LN_EPS);
    float2 gg = *(const float2*)(g0 + j0);
    float2 bb = *(const float2*)(bb0 + j0);
    float h0 = d0 * rstd * gg.x + bb.x;
    float h1 = d1 * rstd * gg.y + bb.y;
    unsigned int pk = (unsigned int)f2bf(h0) | ((unsigned int)f2bf(h1) << 16);
    ((unsigned int*)(ahn + (size_t)node * 256))[64 + lane] = pk;
}

// ---- agg half of ahn[n] = bf16( invdeg[n] * sum hn_bf16[src] ) : one wave/node ----
__global__ __launch_bounds__(256) void gather_kernel(
        const int* __restrict__ rowptr, const int* __restrict__ csr_src,
        unsigned short* __restrict__ ahn, const float* __restrict__ invdeg) {
    int wave = threadIdx.x >> 6, lane = threadIdx.x & 63;
    int node = blockIdx.x * 4 + wave;
    if (node >= N_NODES) return;
    int beg = rowptr[node], end = rowptr[node + 1];
    float ax = 0.f, ay = 0.f;
    int i = beg;
    for (; i + 4 <= end; i += 4) {
        int s0 = csr_src[i], s1 = csr_src[i + 1], s2 = csr_src[i + 2], s3 = csr_src[i + 3];
        unsigned int u0 = ((const unsigned int*)(ahn + (size_t)s0 * 256))[64 + lane];
        unsigned int u1 = ((const unsigned int*)(ahn + (size_t)s1 * 256))[64 + lane];
        unsigned int u2 = ((const unsigned int*)(ahn + (size_t)s2 * 256))[64 + lane];
        unsigned int u3 = ((const unsigned int*)(ahn + (size_t)s3 * 256))[64 + lane];
        ax += (bf_lo(u0) + bf_lo(u1)) + (bf_lo(u2) + bf_lo(u3));
        ay += (bf_hi(u0) + bf_hi(u1)) + (bf_hi(u2) + bf_hi(u3));
    }
    for (; i < end; ++i) {
        unsigned int u = ((const unsigned int*)(ahn + (size_t)csr_src[i] * 256))[64 + lane];
        ax += bf_lo(u); ay += bf_hi(u);
    }
    float inv = invdeg[node];
    unsigned int pk = (unsigned int)f2bf(ax * inv) | ((unsigned int)f2bf(ay * inv) << 16);
    ((unsigned int*)(ahn + (size_t)node * 256))[lane] = pk;
}

// ---- conv: D = ahn(128x256 bf16) @ BT^T; h=relu(hres+D+bl); fused LN -> ahn hn-half ----
__global__ __launch_bounds__(256) void conv_mfma_kernel(
        const float* __restrict__ hres, unsigned short* __restrict__ ahn,
        const unsigned short* __restrict__ BT, const float* __restrict__ bl,
        const float* __restrict__ lng, const float* __restrict__ lnb,
        float* __restrict__ h, int do_ln) {
    __shared__ unsigned short s_a[128 * 64];   // 16 KB, XOR-swizzled 16B groups
    __shared__ unsigned short s_b[128 * 64];   // 16 KB
    __shared__ float s_bl[128], s_g[128], s_bb[128];
    int tid = threadIdx.x;
    int n0 = blockIdx.x * 128;
    if (tid < 128) {
        s_bl[tid] = bl[tid];
        s_g[tid]  = do_ln ? lng[tid] : 0.f;
        s_bb[tid] = do_ln ? lnb[tid] : 0.f;
    }
    int w = tid >> 6, lane = tid & 63;
    int q = lane >> 4, c0 = lane & 15;

    f32x4 acc[2][8];
    #pragma unroll
    for (int rt = 0; rt < 2; ++rt)
        #pragma unroll
        for (int ct = 0; ct < 8; ++ct) acc[rt][ct] = (f32x4){0.f, 0.f, 0.f, 0.f};

    for (int kc = 0; kc < 4; ++kc) {
        __syncthreads();
        // stage A chunk: rows n0..n0+127, k = kc*64..+64 (1024 x 16B pieces)
        #pragma unroll
        for (int p = 0; p < 4; ++p) {
            int f = p * 256 + tid;
            int row = f >> 3, g = f & 7;
            int pos = g ^ (row & 7);
            uint4 v = {0u, 0u, 0u, 0u};
            int node = n0 + row;
            if (node < N_NODES)
                v = *(const uint4*)(ahn + (size_t)node * 256 + kc * 64 + g * 8);
            *(uint4*)(s_a + row * 64 + pos * 8) = v;
        }
        // stage BT chunk: rows n=0..127 (cols of W), same k slice
        #pragma unroll
        for (int p = 0; p < 4; ++p) {
            int f = p * 256 + tid;
            int row = f >> 3, g = f & 7;
            int pos = g ^ (row & 7);
            uint4 v = *(const uint4*)(BT + (size_t)row * 256 + kc * 64 + g * 8);
            *(uint4*)(s_b + row * 64 + pos * 8) = v;
        }
        __syncthreads();
        #pragma unroll
        for (int ks = 0; ks < 2; ++ks) {
            int g = ks * 4 + q;
            bf16x8 af[2], bfr[8];
            #pragma unroll
            for (int rt = 0; rt < 2; ++rt) {
                int row = w * 32 + rt * 16 + c0;
                af[rt] = *(const bf16x8*)(s_a + row * 64 + (g ^ (row & 7)) * 8);
            }
            #pragma unroll
            for (int ct = 0; ct < 8; ++ct) {
                int row = ct * 16 + c0;
                bfr[ct] = *(const bf16x8*)(s_b + row * 64 + (g ^ (row & 7)) * 8);
            }
            #pragma unroll
            for (int rt = 0; rt < 2; ++rt)
                #pragma unroll
                for (int ct = 0; ct < 8; ++ct)
                    acc[rt][ct] = __builtin_amdgcn_mfma_f32_16x16x32_bf16(
                        af[rt], bfr[ct], acc[rt][ct], 0, 0, 0);
        }
    }

    // epilogue: C layout col = ct*16 + c0, row-in-tile = q*4 + reg
    #pragma unroll
    for (int rt = 0; rt < 2; ++rt) {
        #pragma unroll
        for (int reg = 0; reg < 4; ++reg) {
            int nd = n0 + w * 32 + rt * 16 + q * 4 + reg;   // quad-uniform
            if (nd >= N_NODES) continue;
            float o[8];
            float s = 0.f;
            #pragma unroll
            for (int ct = 0; ct < 8; ++ct) {
                int col = ct * 16 + c0;
                float v = acc[rt][ct][reg] + s_bl[col] + hres[(size_t)nd * HID + col];
                v = fmaxf(v, 0.f);
                o[ct] = v;
                h[(size_t)nd * HID + col] = v;
                s += v;
            }
            if (do_ln) {
                #pragma unroll
                for (int off = 1; off < 16; off <<= 1) s += __shfl_xor(s, off, 64);
                float mu = s * (1.0f / HID);
                float qs = 0.f;
                #pragma unroll
                for (int ct = 0; ct < 8; ++ct) { float d = o[ct] - mu; qs += d * d; }
                #pragma unroll
                for (int off = 1; off < 16; off <<= 1) qs += __shfl_xor(qs, off, 64);
                float rstd = rsqrtf(qs * (1.0f / HID) + LN_EPS);
                #pragma unroll
                for (int ct = 0; ct < 8; ++ct) {
                    int col = ct * 16 + c0;
                    float hv = (o[ct] - mu) * rstd * s_g[col] + s_bb[col];
                    ahn[(size_t)nd * 256 + 128 + col] = f2bf(hv);
                }
            }
        }
    }
}

// ---- out = h @ W_out + b_out ----
__global__ void out_proj_kernel(const float* __restrict__ h, const float* __restrict__ W,
                                const float* __restrict__ b, float* __restrict__ out) {
    int t = blockIdx.x * 256 + threadIdx.x;
    if (t >= N_NODES * D_OUT) return;
    int n = t >> 2, d = t & 3;
    float acc = b[d];
    const float* hr = h + (size_t)n * HID;
    #pragma unroll 4
    for (int k = 0; k < HID; ++k) acc += hr[k] * W[k * D_OUT + d];
    out[t] = acc;
}

extern "C" void kernel_launch(void* const* d_in, const int* in_sizes, int n_in,
                              void* d_out, int out_size, void* d_ws, size_t ws_size,
                              hipStream_t stream) {
    const float* x    = (const float*)d_in[0];
    const int*   ei   = (const int*)d_in[1];
    const float* W_in = (const float*)d_in[2];
    const float* b_in = (const float*)d_in[3];
    const float* Wl   = (const float*)d_in[4];
    const float* bl   = (const float*)d_in[5];
    const float* Wr   = (const float*)d_in[6];
    const float* ln_g = (const float*)d_in[7];
    const float* ln_b = (const float*)d_in[8];
    const float* W_out= (const float*)d_in[9];
    const float* b_out= (const float*)d_in[10];
    float* out = (float*)d_out;

    float* ws = (float*)d_ws;
    float* h            = ws;                                    // 6.4M floats
    unsigned short* ahn = (unsigned short*)(h + (size_t)N_NODES * HID);  // [N][256] bf16
    unsigned short* BT  = ahn + (size_t)N_NODES * 256;           // 3 * 128*256 bf16
    float* invdeg       = (float*)(BT + (size_t)N_LAYERS * 128 * 256);
    int*   degi   = (int*)(invdeg + N_NODES);
    int*   rowptr = degi + N_NODES;
    int*   cursor = rowptr + (N_NODES + 1);
    int*   csr_src= cursor + N_NODES;
    int*   bs     = csr_src + N_EDGES;
    int*   boff   = bs + 256;

    const int* src = ei;
    const int* dst = ei + N_EDGES;

    // ---- weight prep (independent) ----
    wprep_kernel<<<N_LAYERS * 128, 256, 0, stream>>>(Wl, Wr, BT);

    // ---- CSR build (once, reused across layers) ----
    hipMemsetAsync(degi, 0, N_NODES * sizeof(int), stream);
    hipMemsetAsync(cursor, 0, N_NODES * sizeof(int), stream);
    degi_kernel<<<(N_EDGES + 255) / 256, 256, 0, stream>>>(dst, degi);
    blocksum_kernel<<<SCAN_BLOCKS, 256, 0, stream>>>(degi, bs);
    scanbs_kernel<<<1, 256, 0, stream>>>(bs, boff);
    rowptr_kernel<<<SCAN_BLOCKS, 256, 0, stream>>>(degi, boff, rowptr, invdeg);
    fill_kernel<<<(N_EDGES + 255) / 256, 256, 0, stream>>>(src, dst, rowptr, cursor, csr_src);

    in_proj_ln_kernel<<<(N_NODES + 3) / 4, 256, 0, stream>>>(
        x, W_in, b_in, ln_g, ln_b, h, ahn);

    for (int i = 0; i < N_LAYERS; ++i) {
        gather_kernel<<<(N_NODES + 3) / 4, 256, 0, stream>>>(rowptr, csr_src, ahn, invdeg);
        int do_ln = (i + 1 < N_LAYERS) ? 1 : 0;
        const float* g_next = ln_g + (do_ln ? (size_t)(i + 1) * HID : 0);
        const float* b_next = ln_b + (do_ln ? (size_t)(i + 1) * HID : 0);
        conv_mfma_kernel<<<(N_NODES + 127) / 128, 256, 0, stream>>>(
            h, ahn, BT + (size_t)i * 128 * 256, bl + i * HID,
            g_next, b_next, h, do_ln);
    }

    out_proj_kernel<<<(N_NODES * D_OUT + 255) / 256, 256, 0, stream>>>(h, W_out, b_out, out);
}